// Round 2
// baseline (198.841 us; speedup 1.0000x reference)
//
#include <hip/hip_runtime.h>

// GAE backward scan. B=4096 independent rows, T=2048 steps.
// One WAVE per row (barrier-free): lane L owns elements [32L, 32L+32)
// (128 B contiguous per array -> full-cache-line utilization per lane).
// 1) intra-lane serial backward scan (registers) -> affine map (A, B)
// 2) 6-step __shfl_down suffix-composition scan across the 64 lanes
// 3) replay intra-lane scan with true carry, store adv/ret as float4.
// No LDS, no __syncthreads -> waves never stall on each other.

constexpr float GAMMA = 0.99f;
constexpr float LMBDA = 0.95f;
constexpr int   T     = 2048;
constexpr int   EPL   = 32;        // elements per lane
constexpr int   ROWS_PER_BLOCK = 4;

__global__ __launch_bounds__(256, 4) void gae_kernel(
    const float* __restrict__ reward,
    const int*   __restrict__ term,
    const float* __restrict__ value,
    const float* __restrict__ next_value,
    float* __restrict__ adv_out,
    float* __restrict__ ret_out,
    int B)
{
    const int wave = threadIdx.x >> 6;
    const int lane = threadIdx.x & 63;
    const int row  = blockIdx.x * ROWS_PER_BLOCK + wave;
    if (row >= B) return;

    const size_t base = (size_t)row * T + (size_t)lane * EPL;
    const float4* r4 = (const float4*)(reward     + base);
    const int4*   t4 = (const int4*  )(term       + base);
    const float4* v4 = (const float4*)(value      + base);
    const float4* n4 = (const float4*)(next_value + base);

    // Load 128 B per array per lane; fold 4 inputs into (c, delta, v).
    float c[EPL], delta[EPL], vv[EPL];
    #pragma unroll
    for (int q = 0; q < EPL / 4; ++q) {
        float4 r  = r4[q];
        int4   tm = t4[q];
        float4 v  = v4[q];
        float4 nv = n4[q];
        float nd0 = 1.f - (float)tm.x, nd1 = 1.f - (float)tm.y;
        float nd2 = 1.f - (float)tm.z, nd3 = 1.f - (float)tm.w;
        c[4*q+0] = (GAMMA * LMBDA) * nd0;
        c[4*q+1] = (GAMMA * LMBDA) * nd1;
        c[4*q+2] = (GAMMA * LMBDA) * nd2;
        c[4*q+3] = (GAMMA * LMBDA) * nd3;
        delta[4*q+0] = fmaf(GAMMA * nv.x, nd0, r.x) - v.x;
        delta[4*q+1] = fmaf(GAMMA * nv.y, nd1, r.y) - v.y;
        delta[4*q+2] = fmaf(GAMMA * nv.z, nd2, r.z) - v.z;
        delta[4*q+3] = fmaf(GAMMA * nv.w, nd3, r.w) - v.w;
        vv[4*q+0] = v.x; vv[4*q+1] = v.y; vv[4*q+2] = v.z; vv[4*q+3] = v.w;
    }

    // Intra-lane backward scan with zero carry -> affine map f(x) = A + Bc*x.
    float A = 0.f, Bc = 1.f;
    #pragma unroll
    for (int t = EPL - 1; t >= 0; --t) {
        A  = fmaf(c[t], A, delta[t]);
        Bc *= c[t];
    }

    // Inclusive suffix-composition scan across lanes (lane -> lanes [lane..63]).
    // own covers earlier t, right covers later t: (own ∘ right)(x).
    #pragma unroll
    for (int off = 1; off < 64; off <<= 1) {
        float a2 = __shfl_down(A,  off, 64);
        float b2 = __shfl_down(Bc, off, 64);
        if (lane + off < 64) {
            A  = fmaf(Bc, a2, A);
            Bc *= b2;
        }
    }
    // Carry into this lane's chunk = suffix result of lane+1 applied to 0.
    float gin = __shfl_down(A, 1, 64);
    if (lane == 63) gin = 0.f;

    // Replay with true carry; store backward, one float4 per 4 elements.
    float4* advp = (float4*)(adv_out + base);
    float4* retp = (float4*)(ret_out + base);
    float g = gin;
    #pragma unroll
    for (int q = EPL / 4 - 1; q >= 0; --q) {
        float a3, a2, a1, a0;
        g = fmaf(c[4*q+3], g, delta[4*q+3]); a3 = g;
        g = fmaf(c[4*q+2], g, delta[4*q+2]); a2 = g;
        g = fmaf(c[4*q+1], g, delta[4*q+1]); a1 = g;
        g = fmaf(c[4*q+0], g, delta[4*q+0]); a0 = g;
        advp[q] = make_float4(a0, a1, a2, a3);
        retp[q] = make_float4(a0 + vv[4*q+0], a1 + vv[4*q+1],
                              a2 + vv[4*q+2], a3 + vv[4*q+3]);
    }
}

extern "C" void kernel_launch(void* const* d_in, const int* in_sizes, int n_in,
                              void* d_out, int out_size, void* d_ws, size_t ws_size,
                              hipStream_t stream) {
    const float* reward     = (const float*)d_in[0];
    const int*   term       = (const int*  )d_in[1];
    const float* value      = (const float*)d_in[2];
    const float* next_value = (const float*)d_in[3];

    const int BT = in_sizes[0];
    const int B  = BT / T;

    float* adv = (float*)d_out;
    float* ret = adv + BT;

    const int grid = (B + ROWS_PER_BLOCK - 1) / ROWS_PER_BLOCK;
    gae_kernel<<<grid, 64 * ROWS_PER_BLOCK, 0, stream>>>(
        reward, term, value, next_value, adv, ret, B);
}

// Round 3
// 176.795 us; speedup vs baseline: 1.1247x; 1.1247x over previous
//
#include <hip/hip_runtime.h>

// GAE backward scan. B=4096 independent rows, T=2048 steps.
// One 256-thread block per row; thread j owns elements [8j, 8j+8)
// (R1 layout: proven exact-ideal HBM write traffic, 4096-block grid).
// Scan: per-thread serial (registers) -> per-wave __shfl_down suffix
// composition (6 steps, barrier-free) -> ONE __syncthreads to combine
// the 4 wave-affines via LDS. 1 barrier vs R1's 16.

constexpr float GAMMA = 0.99f;
constexpr float LMBDA = 0.95f;
constexpr int   T     = 2048;
constexpr int   TPB   = 256;
constexpr int   E     = T / TPB;        // 8 elements per thread
constexpr int   NW    = TPB / 64;       // 4 waves per block

__global__ __launch_bounds__(TPB) void gae_kernel(
    const float* __restrict__ reward,
    const int*   __restrict__ term,
    const float* __restrict__ value,
    const float* __restrict__ next_value,
    float* __restrict__ adv_out,
    float* __restrict__ ret_out)
{
    const int j    = threadIdx.x;
    const int wave = j >> 6;
    const int lane = j & 63;
    const size_t base = (size_t)blockIdx.x * T + (size_t)j * E;

    // Coalesced loads: 2 consecutive float4 per array per thread.
    float4 rA = ((const float4*)(reward     + base))[0];
    float4 rB = ((const float4*)(reward     + base))[1];
    int4   tA = ((const int4*  )(term       + base))[0];
    int4   tB = ((const int4*  )(term       + base))[1];
    float4 vA = ((const float4*)(value      + base))[0];
    float4 vB = ((const float4*)(value      + base))[1];
    float4 nA = ((const float4*)(next_value + base))[0];
    float4 nB = ((const float4*)(next_value + base))[1];

    float r [E] = {rA.x, rA.y, rA.z, rA.w, rB.x, rB.y, rB.z, rB.w};
    float nd[E] = {1.f - (float)tA.x, 1.f - (float)tA.y, 1.f - (float)tA.z, 1.f - (float)tA.w,
                   1.f - (float)tB.x, 1.f - (float)tB.y, 1.f - (float)tB.z, 1.f - (float)tB.w};
    float v [E] = {vA.x, vA.y, vA.z, vA.w, vB.x, vB.y, vB.z, vB.w};
    float nv[E] = {nA.x, nA.y, nA.z, nA.w, nB.x, nB.y, nB.z, nB.w};

    // Intra-thread backward scan, zero carry. loc[t] = local gae,
    // P[t] = product of c over [t..E-1].
    float loc[E], P[E];
    {
        float g = 0.f, p = 1.f;
        #pragma unroll
        for (int t = E - 1; t >= 0; --t) {
            float c     = (GAMMA * LMBDA) * nd[t];
            float delta = fmaf(GAMMA * nv[t], nd[t], r[t]) - v[t];
            g = fmaf(c, g, delta);
            p *= c;
            loc[t] = g;
            P[t]   = p;
        }
    }

    // Per-wave inclusive suffix-composition scan of (A, B) = (loc[0], P[0]).
    // (own ∘ right)(x) = A1 + B1*(A2 + B2*x).
    float A = loc[0], Bc = P[0];
    #pragma unroll
    for (int off = 1; off < 64; off <<= 1) {
        float a2 = __shfl_down(A,  off, 64);
        float b2 = __shfl_down(Bc, off, 64);
        if (lane + off < 64) {
            A  = fmaf(Bc, a2, A);
            Bc *= b2;
        }
    }

    // Lane 0 holds the whole wave's affine. One barrier to share.
    __shared__ float sA[NW], sB[NW];
    if (lane == 0) { sA[wave] = A; sB[wave] = Bc; }

    // Exclusive suffix within the wave (from lane+1); lane 63 = identity.
    float eA = __shfl_down(A,  1, 64);
    float eB = __shfl_down(Bc, 1, 64);
    if (lane == 63) { eA = 0.f; eB = 1.f; }

    __syncthreads();

    // Carry entering this wave = composition of wave-affines to the right, at 0.
    float wcarry = 0.f;
    #pragma unroll
    for (int w = NW - 1; w > 0; --w) {
        if (w > wave) wcarry = fmaf(sB[w], wcarry, sA[w]);
    }

    // Carry entering this thread's chunk.
    const float gin = fmaf(eB, wcarry, eA);

    // adv[t] = loc[t] + P[t]*gin — independent, stores issue back-to-back.
    float adv[E], ret[E];
    #pragma unroll
    for (int t = 0; t < E; ++t) {
        adv[t] = fmaf(P[t], gin, loc[t]);
        ret[t] = adv[t] + v[t];
    }

    ((float4*)(adv_out + base))[0] = make_float4(adv[0], adv[1], adv[2], adv[3]);
    ((float4*)(adv_out + base))[1] = make_float4(adv[4], adv[5], adv[6], adv[7]);
    ((float4*)(ret_out + base))[0] = make_float4(ret[0], ret[1], ret[2], ret[3]);
    ((float4*)(ret_out + base))[1] = make_float4(ret[4], ret[5], ret[6], ret[7]);
}

extern "C" void kernel_launch(void* const* d_in, const int* in_sizes, int n_in,
                              void* d_out, int out_size, void* d_ws, size_t ws_size,
                              hipStream_t stream) {
    const float* reward     = (const float*)d_in[0];
    const int*   term       = (const int*  )d_in[1];
    const float* value      = (const float*)d_in[2];
    const float* next_value = (const float*)d_in[3];

    const int BT = in_sizes[0];
    const int B  = BT / T;

    float* adv = (float*)d_out;
    float* ret = adv + BT;

    gae_kernel<<<B, TPB, 0, stream>>>(reward, term, value, next_value, adv, ret);
}